// Round 1
// baseline (168.754 us; speedup 1.0000x reference)
//
#include <hip/hip_runtime.h>

#define BD 64
#define SD 512
#define DD 1024
#define HD 1024
#define TD 9

__device__ __forceinline__ float rl(float x, int l) {
    return __uint_as_float(__builtin_amdgcn_readlane(__float_as_uint(x), l));
}

// ---------------- Kernel A: W12t[t][d] = sum_h W1[d][h]*W2[h][t]; b12 ----------------
__global__ __launch_bounds__(256) void k_w12(const float* __restrict__ W1,
                                             const float* __restrict__ b1,
                                             const float* __restrict__ W2,
                                             const float* __restrict__ b2,
                                             float* __restrict__ W12t,
                                             float* __restrict__ b12) {
    __shared__ float sh_w2[HD * TD];      // 36 KiB
    __shared__ float red[256 * TD];       // 9 KiB
    const int tid = threadIdx.x;
    const int d = blockIdx.x;             // 0..1023 = W1 rows, 1024 = b1

    for (int i = tid; i < HD * TD / 4; i += 256)
        ((float4*)sh_w2)[i] = ((const float4*)W2)[i];
    __syncthreads();

    const float* row = (d < DD) ? (W1 + (size_t)d * HD) : b1;
    float4 x = ((const float4*)row)[tid];  // h = tid*4 .. tid*4+3

    float acc[TD];
#pragma unroll
    for (int t = 0; t < TD; t++) acc[t] = 0.f;
#pragma unroll
    for (int u = 0; u < 4; u++) {
        float xv = (&x.x)[u];
        int h = tid * 4 + u;
#pragma unroll
        for (int t = 0; t < TD; t++) acc[t] += xv * sh_w2[h * TD + t];
    }
#pragma unroll
    for (int t = 0; t < TD; t++) red[tid * TD + t] = acc[t];
    __syncthreads();

    if (tid < TD) {
        float s = 0.f;
        for (int i = 0; i < 256; i++) s += red[i * TD + tid];
        if (d < DD) W12t[tid * DD + d] = s;
        else        b12[tid] = s + b2[tid];
    }
}

// ---------------- Kernel B: logits[row][t] = X[row]·W12t[t] + b12[t] ----------------
__global__ __launch_bounds__(256) void k_gemm2(const float* __restrict__ X,
                                               const float* __restrict__ W12t,
                                               const float* __restrict__ b12,
                                               float* __restrict__ logits) {
    __shared__ float wt[TD][DD];  // 36 KiB, [t][d]
    __shared__ float bb[TD];

    for (int i = threadIdx.x; i < TD * DD / 4; i += 256)
        ((float4*)&wt[0][0])[i] = ((const float4*)W12t)[i];
    if (threadIdx.x < TD) bb[threadIdx.x] = b12[threadIdx.x];
    __syncthreads();

    const int wave = threadIdx.x >> 6;
    const int lane = threadIdx.x & 63;
    const int g = lane >> 3;       // 8 rows per wave
    const int l8 = lane & 7;       // 8 lanes per row
    const int row = blockIdx.x * 32 + wave * 8 + g;

    const float4* xr = (const float4*)(X + (size_t)row * DD);

    float acc[TD];
#pragma unroll
    for (int t = 0; t < TD; t++) acc[t] = 0.f;

#pragma unroll 4
    for (int k = 0; k < 32; k++) {
        int d4 = l8 + k * 8;              // float4 index into the row
        float4 x = xr[d4];
#pragma unroll
        for (int t = 0; t < TD; t++) {
            float4 w = *(const float4*)&wt[t][d4 * 4];
            acc[t] += x.x * w.x + x.y * w.y + x.z * w.z + x.w * w.w;
        }
    }

#pragma unroll
    for (int t = 0; t < TD; t++) {
        float v = acc[t];
        v += __shfl_xor(v, 1);
        v += __shfl_xor(v, 2);
        v += __shfl_xor(v, 4);
        acc[t] = v;
    }

    float* out = logits + (size_t)row * TD;
    if (l8 < 8) out[l8] = acc[l8] + bb[l8];
    if (l8 == 0) out[8] = acc[8] + bb[8];
}

// ---------------- Kernel C: CRF per-batch (score - log_z) ----------------
__global__ __launch_bounds__(64) void k_crf(const float* __restrict__ logits,
                                            const int* __restrict__ labels,
                                            const int* __restrict__ maskp,
                                            const float* __restrict__ startp,
                                            const float* __restrict__ endp,
                                            const float* __restrict__ transp,
                                            float* __restrict__ diff) {
    __shared__ float em[SD * TD];   // 18 KiB
    __shared__ float tr[TD * TD];
    __shared__ float st[TD], en[TD];
    __shared__ int tg[SD];
    __shared__ int mk[SD];

    const int b = blockIdx.x;
    const int lane = threadIdx.x;

    const float* src = logits + (size_t)b * SD * TD;
    for (int i = lane; i < SD * TD; i += 64) em[i] = src[i];
    for (int i = lane; i < SD; i += 64) {
        tg[i] = labels[b * SD + i];
        mk[i] = maskp[b * SD + i];
    }
    for (int i = lane; i < TD * TD; i += 64) tr[i] = transp[i];
    if (lane < TD) { st[lane] = startp[lane]; en[lane] = endp[lane]; }
    __syncthreads();

    // ---- numerator ----
    float part = 0.f;
    for (int t = 1 + lane; t < SD; t += 64) {
        if (mk[t]) part += tr[tg[t - 1] * TD + tg[t]] + em[t * TD + tg[t]];
    }
#pragma unroll
    for (int m = 1; m < 64; m <<= 1) part += __shfl_xor(part, m);

    int lastt = 0;
    for (int t = lane; t < SD; t += 64) if (mk[t]) lastt = t;
#pragma unroll
    for (int m = 1; m < 64; m <<= 1) lastt = max(lastt, __shfl_xor(lastt, m));

    float score = part + st[tg[0]] + em[tg[0]] + en[tg[lastt]];

    // ---- denominator: forward logsumexp recurrence ----
    const int jj = lane % TD;
    float tc[TD];
#pragma unroll
    for (int i = 0; i < TD; i++) tc[i] = tr[i * TD + jj];

    float va = st[jj] + em[jj];  // alpha at t=0 for tag jj

    for (int t = 1; t < SD; t++) {
        float tmp[TD];
#pragma unroll
        for (int i = 0; i < TD; i++) tmp[i] = rl(va, i) + tc[i];

        float m0 = fmaxf(tmp[0], tmp[1]);
        float m1 = fmaxf(tmp[2], tmp[3]);
        float m2 = fmaxf(tmp[4], tmp[5]);
        float m3 = fmaxf(tmp[6], tmp[7]);
        float mx = fmaxf(fmaxf(fmaxf(m0, m1), fmaxf(m2, m3)), tmp[8]);

        float e0 = __expf(tmp[0] - mx);
        float e1 = __expf(tmp[1] - mx);
        float e2 = __expf(tmp[2] - mx);
        float e3 = __expf(tmp[3] - mx);
        float e4 = __expf(tmp[4] - mx);
        float e5 = __expf(tmp[5] - mx);
        float e6 = __expf(tmp[6] - mx);
        float e7 = __expf(tmp[7] - mx);
        float e8 = __expf(tmp[8] - mx);
        float s = (((e0 + e1) + (e2 + e3)) + ((e4 + e5) + (e6 + e7))) + e8;

        float na = mx + __logf(s) + em[t * TD + jj];
        va = (mk[t] != 0) ? na : va;
    }

    // ---- log_z = LSE_j(alpha_j + end_j) ----
    float fv = va + en[jj];
    float f[TD];
#pragma unroll
    for (int i = 0; i < TD; i++) f[i] = rl(fv, i);
    float m0 = fmaxf(f[0], f[1]);
    float m1 = fmaxf(f[2], f[3]);
    float m2 = fmaxf(f[4], f[5]);
    float m3 = fmaxf(f[6], f[7]);
    float mx = fmaxf(fmaxf(fmaxf(m0, m1), fmaxf(m2, m3)), f[8]);
    float s = 0.f;
#pragma unroll
    for (int i = 0; i < TD; i++) s += __expf(f[i] - mx);
    float logz = mx + __logf(s);

    if (lane == 0) diff[b] = score - logz;
}

// ---------------- Kernel D: loss = -mean(diff) ----------------
__global__ __launch_bounds__(64) void k_loss(const float* __restrict__ diff,
                                             float* __restrict__ out) {
    float v = (threadIdx.x < BD) ? diff[threadIdx.x] : 0.f;
#pragma unroll
    for (int m = 1; m < 64; m <<= 1) v += __shfl_xor(v, m);
    if (threadIdx.x == 0) out[0] = -v / (float)BD;
}

extern "C" void kernel_launch(void* const* d_in, const int* in_sizes, int n_in,
                              void* d_out, int out_size, void* d_ws, size_t ws_size,
                              hipStream_t stream) {
    const float* X      = (const float*)d_in[0];
    const int*   labels = (const int*)d_in[1];
    const int*   maskp  = (const int*)d_in[2];
    const float* W1     = (const float*)d_in[3];
    const float* b1     = (const float*)d_in[4];
    const float* W2     = (const float*)d_in[5];
    const float* b2     = (const float*)d_in[6];
    const float* startp = (const float*)d_in[7];
    const float* endp   = (const float*)d_in[8];
    const float* transp = (const float*)d_in[9];

    float* out = (float*)d_out;
    float* ws = (float*)d_ws;

    float* diff = ws;                 // 64 floats
    float* W12t = ws + 64;            // 9216 floats, [t][d]
    float* b12  = ws + 64 + DD * TD;  // 9 floats
    float* logits = out + 1;          // [B,S,T] fp32

    hipLaunchKernelGGL(k_w12, dim3(DD + 1), dim3(256), 0, stream,
                       W1, b1, W2, b2, W12t, b12);
    hipLaunchKernelGGL(k_gemm2, dim3(BD * SD / 32), dim3(256), 0, stream,
                       X, W12t, b12, logits);
    hipLaunchKernelGGL(k_crf, dim3(BD), dim3(64), 0, stream,
                       logits, labels, maskp, startp, endp, transp, diff);
    hipLaunchKernelGGL(k_loss, dim3(1), dim3(64), 0, stream, diff, out);
}

// Round 2
// 61.480 us; speedup vs baseline: 2.7449x; 2.7449x over previous
//
#include <hip/hip_runtime.h>

#define BD 64
#define SD 512
#define DD 1024
#define HD 1024
#define TD 9
#define NSEG 8
#define SEGL 64
#define NEGI -1e30f

__device__ __forceinline__ float lse9(const float v[9]) {
    float m0 = fmaxf(v[0], v[1]);
    float m1 = fmaxf(v[2], v[3]);
    float m2 = fmaxf(v[4], v[5]);
    float m3 = fmaxf(v[6], v[7]);
    float mx = fmaxf(fmaxf(m0, m1), fmaxf(fmaxf(m2, m3), v[8]));
    float s = __expf(v[0] - mx) + __expf(v[1] - mx) + __expf(v[2] - mx)
            + __expf(v[3] - mx) + __expf(v[4] - mx) + __expf(v[5] - mx)
            + __expf(v[6] - mx) + __expf(v[7] - mx) + __expf(v[8] - mx);
    return mx + __logf(s);
}

// ---------------- Kernel A: W12t[t][d] = sum_h W1[d][h]*W2[h][t]; b12 ----------------
__global__ __launch_bounds__(256) void k_w12(const float* __restrict__ W1,
                                             const float* __restrict__ b1,
                                             const float* __restrict__ W2,
                                             const float* __restrict__ b2,
                                             float* __restrict__ W12t,
                                             float* __restrict__ b12) {
    __shared__ float sh_w2[HD * TD];
    __shared__ float red[256 * TD];
    const int tid = threadIdx.x;
    const int d = blockIdx.x;             // 0..1023 = W1 rows, 1024 = b1

    for (int i = tid; i < HD * TD / 4; i += 256)
        ((float4*)sh_w2)[i] = ((const float4*)W2)[i];
    __syncthreads();

    const float* row = (d < DD) ? (W1 + (size_t)d * HD) : b1;
    float4 x = ((const float4*)row)[tid];

    float acc[TD];
#pragma unroll
    for (int t = 0; t < TD; t++) acc[t] = 0.f;
#pragma unroll
    for (int u = 0; u < 4; u++) {
        float xv = (&x.x)[u];
        int h = tid * 4 + u;
#pragma unroll
        for (int t = 0; t < TD; t++) acc[t] += xv * sh_w2[h * TD + t];
    }
#pragma unroll
    for (int t = 0; t < TD; t++) red[tid * TD + t] = acc[t];
    __syncthreads();

    if (tid < TD) {
        float s = 0.f;
        for (int i = 0; i < 256; i++) s += red[i * TD + tid];
        if (d < DD) W12t[tid * DD + d] = s;
        else        b12[tid] = s + b2[tid];
    }
}

// ---------------- Kernel B: logits[row][t] = X[row]·W12t[t] + b12[t] ----------------
__global__ __launch_bounds__(256) void k_gemm2(const float* __restrict__ X,
                                               const float* __restrict__ W12t,
                                               const float* __restrict__ b12,
                                               float* __restrict__ logits) {
    __shared__ float wt[TD][DD];
    __shared__ float bb[TD];

    for (int i = threadIdx.x; i < TD * DD / 4; i += 256)
        ((float4*)&wt[0][0])[i] = ((const float4*)W12t)[i];
    if (threadIdx.x < TD) bb[threadIdx.x] = b12[threadIdx.x];
    __syncthreads();

    const int wave = threadIdx.x >> 6;
    const int lane = threadIdx.x & 63;
    const int g = lane >> 3;
    const int l8 = lane & 7;
    const int row = blockIdx.x * 32 + wave * 8 + g;

    const float4* xr = (const float4*)(X + (size_t)row * DD);

    float acc[TD];
#pragma unroll
    for (int t = 0; t < TD; t++) acc[t] = 0.f;

#pragma unroll 4
    for (int k = 0; k < 32; k++) {
        int d4 = l8 + k * 8;
        float4 x = xr[d4];
#pragma unroll
        for (int t = 0; t < TD; t++) {
            float4 w = *(const float4*)&wt[t][d4 * 4];
            acc[t] += x.x * w.x + x.y * w.y + x.z * w.z + x.w * w.w;
        }
    }

#pragma unroll
    for (int t = 0; t < TD; t++) {
        float v = acc[t];
        v += __shfl_xor(v, 1);
        v += __shfl_xor(v, 2);
        v += __shfl_xor(v, 4);
        acc[t] = v;
    }

    float* out = logits + (size_t)row * TD;
    if (l8 < 8) out[l8] = acc[l8] + bb[l8];
    if (l8 == 0) out[8] = acc[8] + bb[8];
}

// ---------------- Kernel C1: per-segment semiring matrix product (tree) ----------------
// Leaves l = 0..510 are steps t = l+1 (M_t[i][j] = trans[i][j] + em_t[j], identity if
// mask==0); leaf 511 is identity padding. Block (b,s) reduces leaves [s*64, s*64+64).
__global__ __launch_bounds__(256) void k_crf_seg(const float* __restrict__ logits,
                                                 const int* __restrict__ maskp,
                                                 const float* __restrict__ transp,
                                                 float* __restrict__ segP) {
    const int blk = blockIdx.x;
    const int b = blk >> 3, s = blk & 7;
    const int tid = threadIdx.x;

    __shared__ float tr[81];
    __shared__ float em[SEGL * 9];
    __shared__ int   mk[SEGL];
    __shared__ float bufA[32 * 81];
    __shared__ float bufB[16 * 81];

    const int t0 = s * SEGL + 1;  // first global step covered by this segment

    for (int i = tid; i < SEGL * 9; i += 256) {
        int q = i / 9, j = i - q * 9;
        int t = t0 + q;
        em[i] = (t < SD) ? logits[((size_t)b * SD + t) * TD + j] : 0.f;
    }
    if (tid < SEGL) {
        int t = t0 + tid;
        mk[tid] = (t < SD) ? maskp[b * SD + t] : 0;
    }
    if (tid < 81) tr[tid] = transp[tid];
    __syncthreads();

    // level 1: 32 products directly from leaf definitions
    for (int e = tid; e < 32 * 81; e += 256) {
        int p = e / 81, r = e - p * 81;
        int i = r / 9, j = r - i * 9;
        int la = 2 * p, lb = 2 * p + 1;
        int mA = mk[la], mB = mk[lb];
        float out;
        if (mA && mB) {
            float v[9];
#pragma unroll
            for (int k = 0; k < 9; k++)
                v[k] = tr[i * 9 + k] + em[la * 9 + k] + tr[k * 9 + j];
            out = lse9(v) + em[lb * 9 + j];
        } else if (mA) {
            out = tr[r] + em[la * 9 + j];
        } else if (mB) {
            out = tr[r] + em[lb * 9 + j];
        } else {
            out = (i == j) ? 0.f : NEGI;
        }
        bufA[e] = out;
    }
    __syncthreads();

#define COMBINE(SRC, DST, NP)                                        \
    for (int e = tid; e < (NP) * 81; e += 256) {                     \
        int p = e / 81, r = e - p * 81;                              \
        int i = r / 9, j = r - i * 9;                                \
        const float* Am = (SRC) + (2 * p) * 81;                      \
        const float* Bm = (SRC) + (2 * p + 1) * 81;                  \
        float v[9];                                                  \
        _Pragma("unroll")                                            \
        for (int k = 0; k < 9; k++) v[k] = Am[i * 9 + k] + Bm[k * 9 + j]; \
        (DST)[e] = lse9(v);                                          \
    }                                                                \
    __syncthreads();

    COMBINE(bufA, bufB, 16)   // 32 -> 16
    COMBINE(bufB, bufA, 8)    // 16 -> 8
    COMBINE(bufA, bufB, 4)    // 8  -> 4
    COMBINE(bufB, bufA, 2)    // 4  -> 2

    if (tid < 81) {           // 2 -> 1, write to global
        int i = tid / 9, j = tid - (tid / 9) * 9;
        float v[9];
#pragma unroll
        for (int k = 0; k < 9; k++) v[k] = bufA[i * 9 + k] + bufA[81 + k * 9 + j];
        segP[(size_t)blk * 81 + tid] = lse9(v);
    }
}

// ---------------- Kernel C2: combine 8 segment matrices, log_z, numerator ----------------
__global__ __launch_bounds__(256) void k_crf_fin(const float* __restrict__ logits,
                                                 const int* __restrict__ labels,
                                                 const int* __restrict__ maskp,
                                                 const float* __restrict__ startp,
                                                 const float* __restrict__ endp,
                                                 const float* __restrict__ transp,
                                                 const float* __restrict__ segP,
                                                 float* __restrict__ diff) {
    const int b = blockIdx.x;
    const int tid = threadIdx.x;

    __shared__ float S[8 * 81];
    __shared__ float A4[4 * 81];
    __shared__ float A2[2 * 81];
    __shared__ float P[81];
    __shared__ float finv[81];
    __shared__ float red[256];
    __shared__ int   redi[256];

    for (int i = tid; i < 8 * 81; i += 256) S[i] = segP[(size_t)b * 8 * 81 + i];
    __syncthreads();

    for (int e = tid; e < 4 * 81; e += 256) {
        int p = e / 81, r = e - p * 81;
        int i = r / 9, j = r - i * 9;
        const float* Am = S + (2 * p) * 81;
        const float* Bm = S + (2 * p + 1) * 81;
        float v[9];
#pragma unroll
        for (int k = 0; k < 9; k++) v[k] = Am[i * 9 + k] + Bm[k * 9 + j];
        A4[e] = lse9(v);
    }
    __syncthreads();

    for (int e = tid; e < 2 * 81; e += 256) {
        int p = e / 81, r = e - p * 81;
        int i = r / 9, j = r - i * 9;
        const float* Am = A4 + (2 * p) * 81;
        const float* Bm = A4 + (2 * p + 1) * 81;
        float v[9];
#pragma unroll
        for (int k = 0; k < 9; k++) v[k] = Am[i * 9 + k] + Bm[k * 9 + j];
        A2[e] = lse9(v);
    }
    __syncthreads();

    if (tid < 81) {
        int i = tid / 9, j = tid - (tid / 9) * 9;
        float v[9];
#pragma unroll
        for (int k = 0; k < 9; k++) v[k] = A2[i * 9 + k] + A2[81 + k * 9 + j];
        P[tid] = lse9(v);
    }
    __syncthreads();

    // finv[k*9+j] = alpha0[k] + P[k][j] + end[j]
    if (tid < 81) {
        int k = tid / 9, j = tid - (tid / 9) * 9;
        finv[tid] = startp[k] + logits[(size_t)b * SD * TD + k] + P[tid] + endp[j];
    }

    // numerator partials (gold-path score)
    float part = 0.f;
    for (int t = 1 + tid; t < SD; t += 256) {
        if (maskp[b * SD + t]) {
            int tgp = labels[b * SD + t - 1];
            int tgc = labels[b * SD + t];
            part += transp[tgp * TD + tgc] + logits[((size_t)b * SD + t) * TD + tgc];
        }
    }
    int lastt = 0;
    for (int t = tid; t < SD; t += 256) {
        if (maskp[b * SD + t]) lastt = max(lastt, t);
    }
    red[tid] = part;
    redi[tid] = lastt;
    __syncthreads();

    if (tid < 64) {
        float p4 = red[tid] + red[tid + 64] + red[tid + 128] + red[tid + 192];
        int l4 = max(max(redi[tid], redi[tid + 64]), max(redi[tid + 128], redi[tid + 192]));
#pragma unroll
        for (int m = 1; m < 64; m <<= 1) {
            p4 += __shfl_xor(p4, m);
            l4 = max(l4, __shfl_xor(l4, m));
        }
        // log_z = LSE over 81 entries of finv
        float v1 = finv[tid];
        float v2 = (tid + 64 < 81) ? finv[tid + 64] : NEGI;
        float mx = fmaxf(v1, v2);
#pragma unroll
        for (int m = 1; m < 64; m <<= 1) mx = fmaxf(mx, __shfl_xor(mx, m));
        float ssum = __expf(v1 - mx) + __expf(v2 - mx);
#pragma unroll
        for (int m = 1; m < 64; m <<= 1) ssum += __shfl_xor(ssum, m);
        float logz = mx + __logf(ssum);

        if (tid == 0) {
            int tg0 = labels[b * SD];
            int tgl = labels[b * SD + l4];
            float score = p4 + startp[tg0] + logits[(size_t)b * SD * TD + tg0] + endp[tgl];
            diff[b] = score - logz;
        }
    }
}

// ---------------- Kernel D: loss = -mean(diff) ----------------
__global__ __launch_bounds__(64) void k_loss(const float* __restrict__ diff,
                                             float* __restrict__ out) {
    float v = (threadIdx.x < BD) ? diff[threadIdx.x] : 0.f;
#pragma unroll
    for (int m = 1; m < 64; m <<= 1) v += __shfl_xor(v, m);
    if (threadIdx.x == 0) out[0] = -v / (float)BD;
}

extern "C" void kernel_launch(void* const* d_in, const int* in_sizes, int n_in,
                              void* d_out, int out_size, void* d_ws, size_t ws_size,
                              hipStream_t stream) {
    const float* X      = (const float*)d_in[0];
    const int*   labels = (const int*)d_in[1];
    const int*   maskp  = (const int*)d_in[2];
    const float* W1     = (const float*)d_in[3];
    const float* b1     = (const float*)d_in[4];
    const float* W2     = (const float*)d_in[5];
    const float* b2     = (const float*)d_in[6];
    const float* startp = (const float*)d_in[7];
    const float* endp   = (const float*)d_in[8];
    const float* transp = (const float*)d_in[9];

    float* out = (float*)d_out;
    float* ws = (float*)d_ws;

    float* diff = ws;                       // 64
    float* W12t = ws + 64;                  // 9216
    float* b12  = ws + 64 + DD * TD;        // 9
    float* segP = ws + 64 + DD * TD + 16;   // 64*8*81 floats
    float* logits = out + 1;                // [B,S,T] fp32

    hipLaunchKernelGGL(k_w12, dim3(DD + 1), dim3(256), 0, stream,
                       W1, b1, W2, b2, W12t, b12);
    hipLaunchKernelGGL(k_gemm2, dim3(BD * SD / 32), dim3(256), 0, stream,
                       X, W12t, b12, logits);
    hipLaunchKernelGGL(k_crf_seg, dim3(BD * NSEG), dim3(256), 0, stream,
                       logits, maskp, transp, segP);
    hipLaunchKernelGGL(k_crf_fin, dim3(BD), dim3(256), 0, stream,
                       logits, labels, maskp, startp, endp, transp, segP, diff);
    hipLaunchKernelGGL(k_loss, dim3(1), dim3(64), 0, stream, diff, out);
}